// Round 2
// baseline (256.594 us; speedup 1.0000x reference)
//
#include <hip/hip_runtime.h>
#include <stdint.h>

#define N_ROWS 65536
#define K_CENT 256
#define D_DIM  256

typedef __attribute__((ext_vector_type(8))) short bf16x8;
typedef __attribute__((ext_vector_type(4))) float f32x4;

__device__ __forceinline__ float bf2f(unsigned short u) {
    union { unsigned int i; float f; } v;
    v.i = ((unsigned int)u) << 16;
    return v.f;
}

__device__ __forceinline__ unsigned short f2bf(float f) {
    union { float f; unsigned int i; } v;
    v.f = f;
    unsigned int r = (v.i + 0x7FFFu + ((v.i >> 16) & 1u)) >> 16;
    return (unsigned short)r;
}

// ---------- c2[k] = sum_d round_bf16(cent[k][d])^2; also emit bf16 copy ----------
__global__ void c2_kernel(const float* __restrict__ cent,
                          float* __restrict__ c2,
                          unsigned short* __restrict__ cent_bf) {
    int row  = blockIdx.x;
    int lane = threadIdx.x; // 64 threads
    const float4 v = *(const float4*)(cent + (size_t)row * D_DIM + lane * 4);
    unsigned short b0 = f2bf(v.x), b1 = f2bf(v.y), b2 = f2bf(v.z), b3 = f2bf(v.w);
    ushort4 bv; bv.x = b0; bv.y = b1; bv.z = b2; bv.w = b3;
    *(ushort4*)(cent_bf + (size_t)row * D_DIM + lane * 4) = bv;
    float f0 = bf2f(b0), f1 = bf2f(b1), f2 = bf2f(b2), f3 = bf2f(b3);
    float s = f0 * f0 + f1 * f1 + f2 * f2 + f3 * f3;
    #pragma unroll
    for (int off = 32; off >= 1; off >>= 1) s += __shfl_xor(s, off, 64);
    if (lane == 0) c2[row] = s;
}

// ---------- pass 1: q = rownorm(1/(1+sse)), colsum partials ----------
// block = 256 threads (4 waves); block tile = 64 rows x 256 cols;
// wave tile = 16 rows x 256 cols (16 col-tiles of 16x16x32 MFMA).
__global__ void pass1_kernel(const float* __restrict__ z,
                             const unsigned short* __restrict__ cent_bf,
                             const float* __restrict__ c2,
                             float* __restrict__ s_col,
                             float* __restrict__ q_out) {
    __shared__ float col_lds[4][K_CENT];

    const int tid  = threadIdx.x;
    const int wave = tid >> 6;
    const int lane = tid & 63;
    const int m15  = lane & 15;   // A row within tile / C col within tile
    const int quad = lane >> 4;   // 0..3
    const int row0 = blockIdx.x * 64 + wave * 16;

    f32x4 acc[16];
    #pragma unroll
    for (int t = 0; t < 16; ++t) acc[t] = (f32x4){0.f, 0.f, 0.f, 0.f};

    const float*          za = z + (size_t)(row0 + m15) * D_DIM + quad * 8;
    const unsigned short* ba = cent_bf + (size_t)m15 * D_DIM + quad * 8;

    float z2p = 0.0f;
    for (int ks = 0; ks < D_DIM; ks += 32) {
        float4 a0 = *(const float4*)(za + ks);
        float4 a1 = *(const float4*)(za + ks + 4);
        bf16x8 afrag;
        unsigned short ub[8];
        ub[0] = f2bf(a0.x); ub[1] = f2bf(a0.y); ub[2] = f2bf(a0.z); ub[3] = f2bf(a0.w);
        ub[4] = f2bf(a1.x); ub[5] = f2bf(a1.y); ub[6] = f2bf(a1.z); ub[7] = f2bf(a1.w);
        #pragma unroll
        for (int j = 0; j < 8; ++j) {
            afrag[j] = (short)ub[j];
            float f = bf2f(ub[j]);
            z2p += f * f;
        }
        #pragma unroll
        for (int t = 0; t < 16; ++t) {
            bf16x8 bfrag = *(const bf16x8*)(ba + (size_t)t * 16 * D_DIM + ks);
            acc[t] = __builtin_amdgcn_mfma_f32_16x16x32_bf16(afrag, bfrag, acc[t], 0, 0, 0);
        }
    }

    // z2 full row sums: reduce over quad bits (lanes sharing m15)
    z2p += __shfl_xor(z2p, 16, 64);
    z2p += __shfl_xor(z2p, 32, 64);
    // lane L now holds z2 for row (row0 + (L&15)); fetch z2 for the 4 C-rows
    float z2r[4];
    #pragma unroll
    for (int r = 0; r < 4; ++r) z2r[r] = __shfl(z2p, quad * 4 + r, 64);

    // epilogue: u = 1/(1+max(sse,0)), row sums
    float rowsum[4] = {0.f, 0.f, 0.f, 0.f};
    #pragma unroll
    for (int t = 0; t < 16; ++t) {
        float c2v = c2[t * 16 + m15];
        #pragma unroll
        for (int r = 0; r < 4; ++r) {
            float sse = z2r[r] + c2v - 2.0f * acc[t][r];
            sse = fmaxf(sse, 0.0f);
            float u = 1.0f / (1.0f + sse);
            acc[t][r] = u;
            rowsum[r] += u;
        }
    }
    // rowsum: reduce over the 16 lanes of the quad (same C-row)
    #pragma unroll
    for (int r = 0; r < 4; ++r) {
        float v = rowsum[r];
        v += __shfl_xor(v, 1, 64);
        v += __shfl_xor(v, 2, 64);
        v += __shfl_xor(v, 4, 64);
        v += __shfl_xor(v, 8, 64);
        rowsum[r] = 1.0f / v;
    }

    // q = u * rinv: store fp32 + column partials
    float colp[16];
    #pragma unroll
    for (int t = 0; t < 16; ++t) {
        float cp = 0.0f;
        #pragma unroll
        for (int r = 0; r < 4; ++r) {
            float qv = acc[t][r] * rowsum[r];
            cp += qv;
            q_out[(size_t)(row0 + quad * 4 + r) * K_CENT + t * 16 + m15] = qv;
        }
        cp += __shfl_xor(cp, 16, 64);  // sum the wave's 16 rows
        cp += __shfl_xor(cp, 32, 64);
        colp[t] = cp;
    }
    if (quad == 0) {
        #pragma unroll
        for (int t = 0; t < 16; ++t) col_lds[wave][t * 16 + lane] = colp[t];
    }
    __syncthreads();
    float sp = col_lds[0][tid] + col_lds[1][tid] + col_lds[2][tid] + col_lds[3][tid];
    atomicAdd(&s_col[tid], sp);
}

// ---------- pass 2: p = rownorm(q^2 / s_col) ----------
__global__ void pass2_kernel(const float* __restrict__ q,
                             const float* __restrict__ s_col,
                             float* __restrict__ p) {
    const int tid  = threadIdx.x;
    const int lane = tid & 63;
    const int wave = tid >> 6;
    const int wid  = blockIdx.x * 4 + wave;

    const float4 sv = *(const float4*)(s_col + lane * 4);
    const float is0 = 1.0f / sv.x, is1 = 1.0f / sv.y,
                is2 = 1.0f / sv.z, is3 = 1.0f / sv.w;

    for (int it = 0; it < 32; ++it) {
        const int row = wid * 32 + it;
        const float4 qv = *(const float4*)(q + (size_t)row * K_CENT + lane * 4);
        float sf0 = qv.x * qv.x * is0, sf1 = qv.y * qv.y * is1;
        float sf2 = qv.z * qv.z * is2, sf3 = qv.w * qv.w * is3;
        float part = sf0 + sf1 + sf2 + sf3;
        #pragma unroll
        for (int off = 32; off >= 1; off >>= 1) part += __shfl_xor(part, off, 64);
        const float rinv = 1.0f / part;
        float4 ov;
        ov.x = sf0 * rinv; ov.y = sf1 * rinv;
        ov.z = sf2 * rinv; ov.w = sf3 * rinv;
        *(float4*)(p + (size_t)row * K_CENT + lane * 4) = ov;
    }
}

extern "C" void kernel_launch(void* const* d_in, const int* in_sizes, int n_in,
                              void* d_out, int out_size, void* d_ws, size_t ws_size,
                              hipStream_t stream) {
    const float* z    = (const float*)d_in[0];
    const float* cent = (const float*)d_in[1];
    float* p_out = (float*)d_out;
    float* q_out = p_out + (size_t)N_ROWS * K_CENT;

    float* c2    = (float*)d_ws;
    float* s_col = c2 + K_CENT;
    unsigned short* cent_bf = (unsigned short*)(s_col + K_CENT);

    hipMemsetAsync(s_col, 0, K_CENT * sizeof(float), stream);
    c2_kernel<<<K_CENT, 64, 0, stream>>>(cent, c2, cent_bf);
    pass1_kernel<<<N_ROWS / 64, 256, 0, stream>>>(z, cent_bf, c2, s_col, q_out);
    pass2_kernel<<<N_ROWS / (4 * 32), 256, 0, stream>>>(q_out, s_col, p_out);
}

// Round 3
// 230.382 us; speedup vs baseline: 1.1138x; 1.1138x over previous
//
#include <hip/hip_runtime.h>
#include <stdint.h>

#define N_ROWS 65536
#define K_CENT 256
#define D_DIM  256

typedef __attribute__((ext_vector_type(8))) short bf16x8;
typedef __attribute__((ext_vector_type(4))) float f32x4;

__device__ __forceinline__ float bf2f(unsigned short u) {
    union { unsigned int i; float f; } v;
    v.i = ((unsigned int)u) << 16;
    return v.f;
}

__device__ __forceinline__ unsigned short f2bf(float f) {
    union { float f; unsigned int i; } v;
    v.f = f;
    unsigned int r = (v.i + 0x7FFFu + ((v.i >> 16) & 1u)) >> 16;
    return (unsigned short)r;
}

// ---------- c2[k] = sum_d round_bf16(cent[k][d])^2; emit SWIZZLED bf16 copy ----
// Swizzle: within each 256-elem row (32 blocks of 8 bf16 = 16 B), block b is
// stored at position b ^ (row & 7). Kills the 512-B row-stride bank aliasing
// when rows are read vertically from LDS (worst case 2-way = free, m136).
__global__ void c2_kernel(const float* __restrict__ cent,
                          float* __restrict__ c2,
                          unsigned short* __restrict__ cent_bf) {
    int row  = blockIdx.x;
    int lane = threadIdx.x; // 64 threads
    const float4 v = *(const float4*)(cent + (size_t)row * D_DIM + lane * 4);
    unsigned short b0 = f2bf(v.x), b1 = f2bf(v.y), b2 = f2bf(v.z), b3 = f2bf(v.w);
    ushort4 bv; bv.x = b0; bv.y = b1; bv.z = b2; bv.w = b3;
    int blk = lane >> 1;                       // 16-B block index (2 lanes/block)
    int pos = row * D_DIM + (((blk ^ (row & 7)) << 3) | ((lane & 1) << 2));
    *(ushort4*)(cent_bf + pos) = bv;
    float f0 = bf2f(b0), f1 = bf2f(b1), f2 = bf2f(b2), f3 = bf2f(b3);
    float s = f0 * f0 + f1 * f1 + f2 * f2 + f3 * f3;
    #pragma unroll
    for (int off = 32; off >= 1; off >>= 1) s += __shfl_xor(s, off, 64);
    if (lane == 0) c2[row] = s;
}

// ---------- pass 1: q = rownorm(1/(1+sse)), colsum partials ----------
// block = 256 threads (4 waves); block tile = 64 rows x 256 cols.
// A fragments persistent in regs; B staged through LDS in 4 x 32KB chunks.
__global__ __launch_bounds__(256, 4) void pass1_kernel(
        const float* __restrict__ z,
        const unsigned short* __restrict__ cent_bf,
        const float* __restrict__ c2,
        float* __restrict__ s_col,
        float* __restrict__ q_out) {
    __shared__ __align__(16) unsigned short bstage[64 * D_DIM]; // 32 KB
    __shared__ float col_lds[4][K_CENT];                        // 4 KB

    const int tid  = threadIdx.x;
    const int wave = tid >> 6;
    const int lane = tid & 63;
    const int m15  = lane & 15;   // A row within tile / C col within tile
    const int quad = lane >> 4;   // 0..3
    const int row0 = blockIdx.x * 64 + wave * 16;

    // ---- load + convert A fragments once; z2 alongside ----
    const float* za = z + (size_t)(row0 + m15) * D_DIM + quad * 8;
    bf16x8 afrag[8];
    float z2p = 0.0f;
    #pragma unroll
    for (int ks = 0; ks < 8; ++ks) {
        float4 a0 = *(const float4*)(za + ks * 32);
        float4 a1 = *(const float4*)(za + ks * 32 + 4);
        float av[8] = {a0.x, a0.y, a0.z, a0.w, a1.x, a1.y, a1.z, a1.w};
        #pragma unroll
        for (int j = 0; j < 8; ++j) {
            unsigned short ub = f2bf(av[j]);
            afrag[ks][j] = (short)ub;
            float f = bf2f(ub);
            z2p += f * f;
        }
    }
    z2p += __shfl_xor(z2p, 16, 64);
    z2p += __shfl_xor(z2p, 32, 64);
    float z2r[4];
    #pragma unroll
    for (int r = 0; r < 4; ++r) z2r[r] = __shfl(z2p, quad * 4 + r, 64);

    f32x4 acc[16];
    #pragma unroll
    for (int t = 0; t < 16; ++t) acc[t] = (f32x4){0.f, 0.f, 0.f, 0.f};

    // ---- 4 chunks of 64 centroids ----
    #pragma unroll
    for (int c = 0; c < 4; ++c) {
        const unsigned short* src = cent_bf + (size_t)c * 64 * D_DIM;
        #pragma unroll
        for (int i = 0; i < 8; ++i) {
            int off = (i * 256 + tid) * 8;   // shorts; 16-B aligned
            *(bf16x8*)&bstage[off] = *(const bf16x8*)&src[off];
        }
        __syncthreads();
        #pragma unroll
        for (int ks = 0; ks < 8; ++ks) {
            #pragma unroll
            for (int t = 0; t < 4; ++t) {
                int r_local = t * 16 + m15;
                int b = quad + ks * 4;
                int pos = r_local * D_DIM + ((b ^ (r_local & 7)) << 3);
                bf16x8 bfrag = *(const bf16x8*)&bstage[pos];
                acc[c * 4 + t] = __builtin_amdgcn_mfma_f32_16x16x32_bf16(
                    afrag[ks], bfrag, acc[c * 4 + t], 0, 0, 0);
            }
        }
        __syncthreads();
    }

    // ---- epilogue (identical math to round 2) ----
    float rowsum[4] = {0.f, 0.f, 0.f, 0.f};
    #pragma unroll
    for (int t = 0; t < 16; ++t) {
        float c2v = c2[t * 16 + m15];
        #pragma unroll
        for (int r = 0; r < 4; ++r) {
            float sse = z2r[r] + c2v - 2.0f * acc[t][r];
            sse = fmaxf(sse, 0.0f);
            float u = 1.0f / (1.0f + sse);
            acc[t][r] = u;
            rowsum[r] += u;
        }
    }
    #pragma unroll
    for (int r = 0; r < 4; ++r) {
        float v = rowsum[r];
        v += __shfl_xor(v, 1, 64);
        v += __shfl_xor(v, 2, 64);
        v += __shfl_xor(v, 4, 64);
        v += __shfl_xor(v, 8, 64);
        rowsum[r] = 1.0f / v;
    }

    float colp[16];
    #pragma unroll
    for (int t = 0; t < 16; ++t) {
        float cp = 0.0f;
        #pragma unroll
        for (int r = 0; r < 4; ++r) {
            float qv = acc[t][r] * rowsum[r];
            cp += qv;
            q_out[(size_t)(row0 + quad * 4 + r) * K_CENT + t * 16 + m15] = qv;
        }
        cp += __shfl_xor(cp, 16, 64);
        cp += __shfl_xor(cp, 32, 64);
        colp[t] = cp;
    }
    if (quad == 0) {
        #pragma unroll
        for (int t = 0; t < 16; ++t) col_lds[wave][t * 16 + lane] = colp[t];
    }
    __syncthreads();
    float sp = col_lds[0][tid] + col_lds[1][tid] + col_lds[2][tid] + col_lds[3][tid];
    atomicAdd(&s_col[tid], sp);
}

// ---------- pass 2: p = rownorm(q^2 / s_col) ----------
// 2048 blocks x 256 threads = 8192 waves; 8 rows per wave, fully unrolled
// so 8 independent load + reduce chains are in flight.
__global__ __launch_bounds__(256) void pass2_kernel(
        const float* __restrict__ q,
        const float* __restrict__ s_col,
        float* __restrict__ p) {
    const int tid  = threadIdx.x;
    const int lane = tid & 63;
    const int wave = tid >> 6;
    const int wid  = blockIdx.x * 4 + wave;   // 0..8191

    const float4 sv = *(const float4*)(s_col + lane * 4);
    const float is0 = 1.0f / sv.x, is1 = 1.0f / sv.y,
                is2 = 1.0f / sv.z, is3 = 1.0f / sv.w;

    const float* qb = q + (size_t)wid * 8 * K_CENT + lane * 4;
    float*       pb = p + (size_t)wid * 8 * K_CENT + lane * 4;

    float4 qv[8];
    #pragma unroll
    for (int r = 0; r < 8; ++r) qv[r] = *(const float4*)(qb + r * K_CENT);

    #pragma unroll
    for (int r = 0; r < 8; ++r) {
        float sf0 = qv[r].x * qv[r].x * is0;
        float sf1 = qv[r].y * qv[r].y * is1;
        float sf2 = qv[r].z * qv[r].z * is2;
        float sf3 = qv[r].w * qv[r].w * is3;
        float part = sf0 + sf1 + sf2 + sf3;
        #pragma unroll
        for (int off = 32; off >= 1; off >>= 1) part += __shfl_xor(part, off, 64);
        const float rinv = 1.0f / part;
        float4 ov;
        ov.x = sf0 * rinv; ov.y = sf1 * rinv;
        ov.z = sf2 * rinv; ov.w = sf3 * rinv;
        *(float4*)(pb + r * K_CENT) = ov;
    }
}

extern "C" void kernel_launch(void* const* d_in, const int* in_sizes, int n_in,
                              void* d_out, int out_size, void* d_ws, size_t ws_size,
                              hipStream_t stream) {
    const float* z    = (const float*)d_in[0];
    const float* cent = (const float*)d_in[1];
    float* p_out = (float*)d_out;
    float* q_out = p_out + (size_t)N_ROWS * K_CENT;

    float* c2    = (float*)d_ws;
    float* s_col = c2 + K_CENT;
    unsigned short* cent_bf = (unsigned short*)(s_col + K_CENT);

    hipMemsetAsync(s_col, 0, K_CENT * sizeof(float), stream);
    c2_kernel<<<K_CENT, 64, 0, stream>>>(cent, c2, cent_bf);
    pass1_kernel<<<N_ROWS / 64, 256, 0, stream>>>(z, cent_bf, c2, s_col, q_out);
    pass2_kernel<<<N_ROWS / (4 * 8), 256, 0, stream>>>(q_out, s_col, p_out);
}

// Round 4
// 220.121 us; speedup vs baseline: 1.1657x; 1.0466x over previous
//
#include <hip/hip_runtime.h>
#include <stdint.h>

#define N_ROWS 65536
#define K_CENT 256
#define D_DIM  256

typedef __attribute__((ext_vector_type(8))) short bf16x8;
typedef __attribute__((ext_vector_type(4))) float f32x4;

__device__ __forceinline__ float bf2f(unsigned short u) {
    union { unsigned int i; float f; } v;
    v.i = ((unsigned int)u) << 16;
    return v.f;
}

__device__ __forceinline__ unsigned short f2bf(float f) {
    union { float f; unsigned int i; } v;
    v.f = f;
    unsigned int r = (v.i + 0x7FFFu + ((v.i >> 16) & 1u)) >> 16;
    return (unsigned short)r;
}

// ---------- c2[k] = sum_d round_bf16(cent[k][d])^2; emit SWIZZLED bf16 copy ----
__global__ void c2_kernel(const float* __restrict__ cent,
                          float* __restrict__ c2,
                          unsigned short* __restrict__ cent_bf) {
    int row  = blockIdx.x;
    int lane = threadIdx.x; // 64 threads
    const float4 v = *(const float4*)(cent + (size_t)row * D_DIM + lane * 4);
    unsigned short b0 = f2bf(v.x), b1 = f2bf(v.y), b2 = f2bf(v.z), b3 = f2bf(v.w);
    ushort4 bv; bv.x = b0; bv.y = b1; bv.z = b2; bv.w = b3;
    int blk = lane >> 1;                       // 16-B block index (2 lanes/block)
    int pos = row * D_DIM + (((blk ^ (row & 7)) << 3) | ((lane & 1) << 2));
    *(ushort4*)(cent_bf + pos) = bv;
    float f0 = bf2f(b0), f1 = bf2f(b1), f2 = bf2f(b2), f3 = bf2f(b3);
    float s = f0 * f0 + f1 * f1 + f2 * f2 + f3 * f3;
    #pragma unroll
    for (int off = 32; off >= 1; off >>= 1) s += __shfl_xor(s, off, 64);
    if (lane == 0) c2[row] = s;
}

// ---------- pass 1: q = rownorm(1/(1+sse)), colsum partials ----------
// block = 256 threads (4 waves); block tile = 64 rows x 256 cols.
// A loads issued in batches of 8 independent float4 (MLP fix, round 4).
__global__ __launch_bounds__(256, 3) void pass1_kernel(
        const float* __restrict__ z,
        const unsigned short* __restrict__ cent_bf,
        const float* __restrict__ c2,
        float* __restrict__ s_col,
        float* __restrict__ q_out) {
    __shared__ __align__(16) unsigned short bstage[64 * D_DIM]; // 32 KB
    __shared__ float col_lds[4][K_CENT];                        // 4 KB

    const int tid  = threadIdx.x;
    const int wave = tid >> 6;
    const int lane = tid & 63;
    const int m15  = lane & 15;   // A row within tile / C col within tile
    const int quad = lane >> 4;   // 0..3
    const int row0 = blockIdx.x * 64 + wave * 16;

    // ---- A fragments: 2 batches of 8 back-to-back float4 loads ----
    const float* za = z + (size_t)(row0 + m15) * D_DIM + quad * 8;
    bf16x8 afrag[8];
    float z2p = 0.0f;
    #pragma unroll
    for (int h = 0; h < 2; ++h) {
        float4 a[8];
        #pragma unroll
        for (int i = 0; i < 4; ++i) {
            a[2 * i]     = *(const float4*)(za + h * 128 + i * 32);
            a[2 * i + 1] = *(const float4*)(za + h * 128 + i * 32 + 4);
        }
        #pragma unroll
        for (int i = 0; i < 4; ++i) {
            const int ks = h * 4 + i;
            const float av[8] = {a[2*i].x, a[2*i].y, a[2*i].z, a[2*i].w,
                                 a[2*i+1].x, a[2*i+1].y, a[2*i+1].z, a[2*i+1].w};
            #pragma unroll
            for (int j = 0; j < 8; ++j) {
                unsigned short ub = f2bf(av[j]);
                afrag[ks][j] = (short)ub;
                float f = bf2f(ub);
                z2p += f * f;
            }
        }
    }
    z2p += __shfl_xor(z2p, 16, 64);
    z2p += __shfl_xor(z2p, 32, 64);
    float z2r[4];
    #pragma unroll
    for (int r = 0; r < 4; ++r) z2r[r] = __shfl(z2p, quad * 4 + r, 64);

    f32x4 acc[16];
    #pragma unroll
    for (int t = 0; t < 16; ++t) acc[t] = (f32x4){0.f, 0.f, 0.f, 0.f};

    // ---- 4 chunks of 64 centroids; staging loads batched 8-deep ----
    #pragma unroll
    for (int c = 0; c < 4; ++c) {
        const unsigned short* src = cent_bf + (size_t)c * 64 * D_DIM;
        bf16x8 st[8];
        #pragma unroll
        for (int i = 0; i < 8; ++i)
            st[i] = *(const bf16x8*)&src[(i * 256 + tid) * 8];
        #pragma unroll
        for (int i = 0; i < 8; ++i)
            *(bf16x8*)&bstage[(i * 256 + tid) * 8] = st[i];
        __syncthreads();
        #pragma unroll
        for (int ks = 0; ks < 8; ++ks) {
            #pragma unroll
            for (int t = 0; t < 4; ++t) {
                int r_local = t * 16 + m15;
                int b = quad + ks * 4;
                int pos = r_local * D_DIM + ((b ^ (r_local & 7)) << 3);
                bf16x8 bfrag = *(const bf16x8*)&bstage[pos];
                acc[c * 4 + t] = __builtin_amdgcn_mfma_f32_16x16x32_bf16(
                    afrag[ks], bfrag, acc[c * 4 + t], 0, 0, 0);
            }
        }
        __syncthreads();
    }

    // ---- epilogue ----
    float rowsum[4] = {0.f, 0.f, 0.f, 0.f};
    #pragma unroll
    for (int t = 0; t < 16; ++t) {
        float c2v = c2[t * 16 + m15];
        #pragma unroll
        for (int r = 0; r < 4; ++r) {
            float sse = z2r[r] + c2v - 2.0f * acc[t][r];
            sse = fmaxf(sse, 0.0f);
            float u = 1.0f / (1.0f + sse);
            acc[t][r] = u;
            rowsum[r] += u;
        }
    }
    #pragma unroll
    for (int r = 0; r < 4; ++r) {
        float v = rowsum[r];
        v += __shfl_xor(v, 1, 64);
        v += __shfl_xor(v, 2, 64);
        v += __shfl_xor(v, 4, 64);
        v += __shfl_xor(v, 8, 64);
        rowsum[r] = 1.0f / v;
    }

    float colp[16];
    #pragma unroll
    for (int t = 0; t < 16; ++t) {
        float cp = 0.0f;
        #pragma unroll
        for (int r = 0; r < 4; ++r) {
            float qv = acc[t][r] * rowsum[r];
            cp += qv;
            q_out[(size_t)(row0 + quad * 4 + r) * K_CENT + t * 16 + m15] = qv;
        }
        cp += __shfl_xor(cp, 16, 64);
        cp += __shfl_xor(cp, 32, 64);
        colp[t] = cp;
    }
    if (quad == 0) {
        #pragma unroll
        for (int t = 0; t < 16; ++t) col_lds[wave][t * 16 + lane] = colp[t];
    }
    __syncthreads();
    float sp = col_lds[0][tid] + col_lds[1][tid] + col_lds[2][tid] + col_lds[3][tid];
    atomicAdd(&s_col[tid], sp);
}

// ---------- pass 2: p = rownorm(q^2 / s_col) ---------- (unchanged, control)
__global__ __launch_bounds__(256) void pass2_kernel(
        const float* __restrict__ q,
        const float* __restrict__ s_col,
        float* __restrict__ p) {
    const int tid  = threadIdx.x;
    const int lane = tid & 63;
    const int wave = tid >> 6;
    const int wid  = blockIdx.x * 4 + wave;   // 0..8191

    const float4 sv = *(const float4*)(s_col + lane * 4);
    const float is0 = 1.0f / sv.x, is1 = 1.0f / sv.y,
                is2 = 1.0f / sv.z, is3 = 1.0f / sv.w;

    const float* qb = q + (size_t)wid * 8 * K_CENT + lane * 4;
    float*       pb = p + (size_t)wid * 8 * K_CENT + lane * 4;

    float4 qv[8];
    #pragma unroll
    for (int r = 0; r < 8; ++r) qv[r] = *(const float4*)(qb + r * K_CENT);

    #pragma unroll
    for (int r = 0; r < 8; ++r) {
        float sf0 = qv[r].x * qv[r].x * is0;
        float sf1 = qv[r].y * qv[r].y * is1;
        float sf2 = qv[r].z * qv[r].z * is2;
        float sf3 = qv[r].w * qv[r].w * is3;
        float part = sf0 + sf1 + sf2 + sf3;
        #pragma unroll
        for (int off = 32; off >= 1; off >>= 1) part += __shfl_xor(part, off, 64);
        const float rinv = 1.0f / part;
        float4 ov;
        ov.x = sf0 * rinv; ov.y = sf1 * rinv;
        ov.z = sf2 * rinv; ov.w = sf3 * rinv;
        *(float4*)(pb + r * K_CENT) = ov;
    }
}

extern "C" void kernel_launch(void* const* d_in, const int* in_sizes, int n_in,
                              void* d_out, int out_size, void* d_ws, size_t ws_size,
                              hipStream_t stream) {
    const float* z    = (const float*)d_in[0];
    const float* cent = (const float*)d_in[1];
    float* p_out = (float*)d_out;
    float* q_out = p_out + (size_t)N_ROWS * K_CENT;

    float* c2    = (float*)d_ws;
    float* s_col = c2 + K_CENT;
    unsigned short* cent_bf = (unsigned short*)(s_col + K_CENT);

    hipMemsetAsync(s_col, 0, K_CENT * sizeof(float), stream);
    c2_kernel<<<K_CENT, 64, 0, stream>>>(cent, c2, cent_bf);
    pass1_kernel<<<N_ROWS / 64, 256, 0, stream>>>(z, cent_bf, c2, s_col, q_out);
    pass2_kernel<<<N_ROWS / (4 * 8), 256, 0, stream>>>(q_out, s_col, p_out);
}

// Round 5
// 219.709 us; speedup vs baseline: 1.1679x; 1.0019x over previous
//
#include <hip/hip_runtime.h>
#include <stdint.h>

#define N_ROWS 65536
#define K_CENT 256
#define D_DIM  256

typedef __attribute__((ext_vector_type(8))) short bf16x8;
typedef __attribute__((ext_vector_type(4))) float f32x4;

__device__ __forceinline__ float bf2f(unsigned short u) {
    union { unsigned int i; float f; } v;
    v.i = ((unsigned int)u) << 16;
    return v.f;
}

__device__ __forceinline__ unsigned short f2bf(float f) {
    union { float f; unsigned int i; } v;
    v.f = f;
    unsigned int r = (v.i + 0x7FFFu + ((v.i >> 16) & 1u)) >> 16;
    return (unsigned short)r;
}

// ---------- c2[k] = sum_d round_bf16(cent[k][d])^2; emit SWIZZLED bf16 copy ----
__global__ void c2_kernel(const float* __restrict__ cent,
                          float* __restrict__ c2,
                          unsigned short* __restrict__ cent_bf) {
    int row  = blockIdx.x;
    int lane = threadIdx.x; // 64 threads
    const float4 v = *(const float4*)(cent + (size_t)row * D_DIM + lane * 4);
    unsigned short b0 = f2bf(v.x), b1 = f2bf(v.y), b2 = f2bf(v.z), b3 = f2bf(v.w);
    ushort4 bv; bv.x = b0; bv.y = b1; bv.z = b2; bv.w = b3;
    int blk = lane >> 1;                       // 16-B block index (2 lanes/block)
    int pos = row * D_DIM + (((blk ^ (row & 7)) << 3) | ((lane & 1) << 2));
    *(ushort4*)(cent_bf + pos) = bv;
    float f0 = bf2f(b0), f1 = bf2f(b1), f2 = bf2f(b2), f3 = bf2f(b3);
    float s = f0 * f0 + f1 * f1 + f2 * f2 + f3 * f3;
    #pragma unroll
    for (int off = 32; off >= 1; off >>= 1) s += __shfl_xor(s, off, 64);
    if (lane == 0) c2[row] = s;
}

// ---------- pass 1: q = rownorm(1/(1+sse)); per-block colsum partials ----------
// Identical to round 4 EXCEPT the atomic fan-in is replaced by a coalesced
// per-block partial store (atomics onto 16 cache lines were the serializer).
__global__ __launch_bounds__(256, 3) void pass1_kernel(
        const float* __restrict__ z,
        const unsigned short* __restrict__ cent_bf,
        const float* __restrict__ c2,
        float* __restrict__ partials,
        float* __restrict__ q_out) {
    __shared__ __align__(16) unsigned short bstage[64 * D_DIM]; // 32 KB
    __shared__ float col_lds[4][K_CENT];                        // 4 KB

    const int tid  = threadIdx.x;
    const int wave = tid >> 6;
    const int lane = tid & 63;
    const int m15  = lane & 15;   // A row within tile / C col within tile
    const int quad = lane >> 4;   // 0..3
    const int row0 = blockIdx.x * 64 + wave * 16;

    // ---- A fragments: 2 batches of 8 back-to-back float4 loads ----
    const float* za = z + (size_t)(row0 + m15) * D_DIM + quad * 8;
    bf16x8 afrag[8];
    float z2p = 0.0f;
    #pragma unroll
    for (int h = 0; h < 2; ++h) {
        float4 a[8];
        #pragma unroll
        for (int i = 0; i < 4; ++i) {
            a[2 * i]     = *(const float4*)(za + h * 128 + i * 32);
            a[2 * i + 1] = *(const float4*)(za + h * 128 + i * 32 + 4);
        }
        #pragma unroll
        for (int i = 0; i < 4; ++i) {
            const int ks = h * 4 + i;
            const float av[8] = {a[2*i].x, a[2*i].y, a[2*i].z, a[2*i].w,
                                 a[2*i+1].x, a[2*i+1].y, a[2*i+1].z, a[2*i+1].w};
            #pragma unroll
            for (int j = 0; j < 8; ++j) {
                unsigned short ub = f2bf(av[j]);
                afrag[ks][j] = (short)ub;
                float f = bf2f(ub);
                z2p += f * f;
            }
        }
    }
    z2p += __shfl_xor(z2p, 16, 64);
    z2p += __shfl_xor(z2p, 32, 64);
    float z2r[4];
    #pragma unroll
    for (int r = 0; r < 4; ++r) z2r[r] = __shfl(z2p, quad * 4 + r, 64);

    f32x4 acc[16];
    #pragma unroll
    for (int t = 0; t < 16; ++t) acc[t] = (f32x4){0.f, 0.f, 0.f, 0.f};

    // ---- 4 chunks of 64 centroids; staging loads batched 8-deep ----
    #pragma unroll
    for (int c = 0; c < 4; ++c) {
        const unsigned short* src = cent_bf + (size_t)c * 64 * D_DIM;
        bf16x8 st[8];
        #pragma unroll
        for (int i = 0; i < 8; ++i)
            st[i] = *(const bf16x8*)&src[(i * 256 + tid) * 8];
        #pragma unroll
        for (int i = 0; i < 8; ++i)
            *(bf16x8*)&bstage[(i * 256 + tid) * 8] = st[i];
        __syncthreads();
        #pragma unroll
        for (int ks = 0; ks < 8; ++ks) {
            #pragma unroll
            for (int t = 0; t < 4; ++t) {
                int r_local = t * 16 + m15;
                int b = quad + ks * 4;
                int pos = r_local * D_DIM + ((b ^ (r_local & 7)) << 3);
                bf16x8 bfrag = *(const bf16x8*)&bstage[pos];
                acc[c * 4 + t] = __builtin_amdgcn_mfma_f32_16x16x32_bf16(
                    afrag[ks], bfrag, acc[c * 4 + t], 0, 0, 0);
            }
        }
        __syncthreads();
    }

    // ---- epilogue ----
    float rowsum[4] = {0.f, 0.f, 0.f, 0.f};
    #pragma unroll
    for (int t = 0; t < 16; ++t) {
        float c2v = c2[t * 16 + m15];
        #pragma unroll
        for (int r = 0; r < 4; ++r) {
            float sse = z2r[r] + c2v - 2.0f * acc[t][r];
            sse = fmaxf(sse, 0.0f);
            float u = 1.0f / (1.0f + sse);
            acc[t][r] = u;
            rowsum[r] += u;
        }
    }
    #pragma unroll
    for (int r = 0; r < 4; ++r) {
        float v = rowsum[r];
        v += __shfl_xor(v, 1, 64);
        v += __shfl_xor(v, 2, 64);
        v += __shfl_xor(v, 4, 64);
        v += __shfl_xor(v, 8, 64);
        rowsum[r] = 1.0f / v;
    }

    float colp[16];
    #pragma unroll
    for (int t = 0; t < 16; ++t) {
        float cp = 0.0f;
        #pragma unroll
        for (int r = 0; r < 4; ++r) {
            float qv = acc[t][r] * rowsum[r];
            cp += qv;
            q_out[(size_t)(row0 + quad * 4 + r) * K_CENT + t * 16 + m15] = qv;
        }
        cp += __shfl_xor(cp, 16, 64);
        cp += __shfl_xor(cp, 32, 64);
        colp[t] = cp;
    }
    if (quad == 0) {
        #pragma unroll
        for (int t = 0; t < 16; ++t) col_lds[wave][t * 16 + lane] = colp[t];
    }
    __syncthreads();
    float sp = col_lds[0][tid] + col_lds[1][tid] + col_lds[2][tid] + col_lds[3][tid];
    partials[(size_t)blockIdx.x * K_CENT + tid] = sp;   // coalesced, NO atomics
}

// ---------- colsum: s_col[k] = sum over 1024 blocks of partials[b][k] ----------
// 16 blocks x 256 threads; block j sums 64 partial rows, then one atomicAdd
// per thread (4096 total, spread over 16 lines x 16 blocks = fine).
__global__ __launch_bounds__(256) void colsum_kernel(
        const float* __restrict__ partials,
        float* __restrict__ s_col) {
    const int tid = threadIdx.x;
    const float* base = partials + (size_t)blockIdx.x * 64 * K_CENT + tid;
    float s = 0.0f;
    #pragma unroll
    for (int h = 0; h < 8; ++h) {
        float v[8];
        #pragma unroll
        for (int i = 0; i < 8; ++i)
            v[i] = base[(h * 8 + i) * K_CENT];
        #pragma unroll
        for (int i = 0; i < 8; ++i) s += v[i];
    }
    atomicAdd(&s_col[tid], s);
}

// ---------- pass 2: p = rownorm(q^2 / s_col) ---------- (unchanged, control)
__global__ __launch_bounds__(256) void pass2_kernel(
        const float* __restrict__ q,
        const float* __restrict__ s_col,
        float* __restrict__ p) {
    const int tid  = threadIdx.x;
    const int lane = tid & 63;
    const int wave = tid >> 6;
    const int wid  = blockIdx.x * 4 + wave;   // 0..8191

    const float4 sv = *(const float4*)(s_col + lane * 4);
    const float is0 = 1.0f / sv.x, is1 = 1.0f / sv.y,
                is2 = 1.0f / sv.z, is3 = 1.0f / sv.w;

    const float* qb = q + (size_t)wid * 8 * K_CENT + lane * 4;
    float*       pb = p + (size_t)wid * 8 * K_CENT + lane * 4;

    float4 qv[8];
    #pragma unroll
    for (int r = 0; r < 8; ++r) qv[r] = *(const float4*)(qb + r * K_CENT);

    #pragma unroll
    for (int r = 0; r < 8; ++r) {
        float sf0 = qv[r].x * qv[r].x * is0;
        float sf1 = qv[r].y * qv[r].y * is1;
        float sf2 = qv[r].z * qv[r].z * is2;
        float sf3 = qv[r].w * qv[r].w * is3;
        float part = sf0 + sf1 + sf2 + sf3;
        #pragma unroll
        for (int off = 32; off >= 1; off >>= 1) part += __shfl_xor(part, off, 64);
        const float rinv = 1.0f / part;
        float4 ov;
        ov.x = sf0 * rinv; ov.y = sf1 * rinv;
        ov.z = sf2 * rinv; ov.w = sf3 * rinv;
        *(float4*)(pb + r * K_CENT) = ov;
    }
}

extern "C" void kernel_launch(void* const* d_in, const int* in_sizes, int n_in,
                              void* d_out, int out_size, void* d_ws, size_t ws_size,
                              hipStream_t stream) {
    const float* z    = (const float*)d_in[0];
    const float* cent = (const float*)d_in[1];
    float* p_out = (float*)d_out;
    float* q_out = p_out + (size_t)N_ROWS * K_CENT;

    float* c2       = (float*)d_ws;
    float* s_col    = c2 + K_CENT;
    unsigned short* cent_bf = (unsigned short*)(s_col + K_CENT);
    float* partials = (float*)(cent_bf + K_CENT * D_DIM);   // 1024*256 floats = 1 MB

    hipMemsetAsync(s_col, 0, K_CENT * sizeof(float), stream);
    c2_kernel<<<K_CENT, 64, 0, stream>>>(cent, c2, cent_bf);
    pass1_kernel<<<N_ROWS / 64, 256, 0, stream>>>(z, cent_bf, c2, partials, q_out);
    colsum_kernel<<<16, 256, 0, stream>>>(partials, s_col);
    pass2_kernel<<<N_ROWS / (4 * 8), 256, 0, stream>>>(q_out, s_col, p_out);
}

// Round 6
// 212.360 us; speedup vs baseline: 1.2083x; 1.0346x over previous
//
#include <hip/hip_runtime.h>
#include <stdint.h>

#define N_ROWS 65536
#define K_CENT 256
#define D_DIM  256

typedef __attribute__((ext_vector_type(8))) short bf16x8;
typedef __attribute__((ext_vector_type(4))) float f32x4;

__device__ __forceinline__ float bf2f(unsigned short u) {
    union { unsigned int i; float f; } v;
    v.i = ((unsigned int)u) << 16;
    return v.f;
}

__device__ __forceinline__ unsigned short f2bf(float f) {
    union { float f; unsigned int i; } v;
    v.f = f;
    unsigned int r = (v.i + 0x7FFFu + ((v.i >> 16) & 1u)) >> 16;
    return (unsigned short)r;
}

// ---------- c2[k] = sum_d round_bf16(cent[k][d])^2; emit LINEAR bf16 copy ----
__global__ void c2_kernel(const float* __restrict__ cent,
                          float* __restrict__ c2,
                          unsigned short* __restrict__ cent_bf) {
    int row  = blockIdx.x;
    int lane = threadIdx.x; // 64 threads
    const float4 v = *(const float4*)(cent + (size_t)row * D_DIM + lane * 4);
    unsigned short b0 = f2bf(v.x), b1 = f2bf(v.y), b2 = f2bf(v.z), b3 = f2bf(v.w);
    ushort4 bv; bv.x = b0; bv.y = b1; bv.z = b2; bv.w = b3;
    *(ushort4*)(cent_bf + (size_t)row * D_DIM + lane * 4) = bv;
    float f0 = bf2f(b0), f1 = bf2f(b1), f2 = bf2f(b2), f3 = bf2f(b3);
    float s = f0 * f0 + f1 * f1 + f2 * f2 + f3 * f3;
    #pragma unroll
    for (int off = 32; off >= 1; off >>= 1) s += __shfl_xor(s, off, 64);
    if (lane == 0) c2[row] = s;
}

// ---------- pass 1: q = rownorm(1/(1+sse)); per-block colsum partials ----------
// v3: fragment-major LDS (conflict-free), 4 blocks/CU single generation,
// all 16 A-loads in flight at once.
__global__ __launch_bounds__(256, 4) void pass1_kernel(
        const float* __restrict__ z,
        const unsigned short* __restrict__ cent_bf,
        const float* __restrict__ c2,
        float* __restrict__ partials,
        float* __restrict__ q_out) {
    // Fragment-major: 16B unit F = ks*256 + t*64 + m15*4 + quad
    // (ks = K-step 0..7, t = col-tile 0..3 within 64-row chunk).
    __shared__ __align__(16) unsigned short bstage[64 * D_DIM]; // 32 KB
    __shared__ float col_lds[4][K_CENT];                        // 4 KB

    const int tid  = threadIdx.x;
    const int wave = tid >> 6;
    const int lane = tid & 63;
    const int m15  = lane & 15;   // A row within tile / C col within tile
    const int quad = lane >> 4;   // 0..3
    const int row0 = blockIdx.x * 64 + wave * 16;

    // ---- A fragments: all 16 float4 loads issued back-to-back ----
    const float* za = z + (size_t)(row0 + m15) * D_DIM + quad * 8;
    float4 a[16];
    #pragma unroll
    for (int i = 0; i < 8; ++i) {
        a[2 * i]     = *(const float4*)(za + i * 32);
        a[2 * i + 1] = *(const float4*)(za + i * 32 + 4);
    }
    bf16x8 afrag[8];
    float z2p = 0.0f;
    #pragma unroll
    for (int ks = 0; ks < 8; ++ks) {
        const float av[8] = {a[2*ks].x, a[2*ks].y, a[2*ks].z, a[2*ks].w,
                             a[2*ks+1].x, a[2*ks+1].y, a[2*ks+1].z, a[2*ks+1].w};
        #pragma unroll
        for (int j = 0; j < 8; ++j) {
            unsigned short ub = f2bf(av[j]);
            afrag[ks][j] = (short)ub;
            float f = bf2f(ub);
            z2p += f * f;
        }
    }
    z2p += __shfl_xor(z2p, 16, 64);
    z2p += __shfl_xor(z2p, 32, 64);
    float z2r[4];
    #pragma unroll
    for (int r = 0; r < 4; ++r) z2r[r] = __shfl(z2p, quad * 4 + r, 64);

    f32x4 acc[16];
    #pragma unroll
    for (int t = 0; t < 16; ++t) acc[t] = (f32x4){0.f, 0.f, 0.f, 0.f};

    // ---- 4 chunks of 64 centroids; fragment-major staging ----
    #pragma unroll
    for (int c = 0; c < 4; ++c) {
        const unsigned short* src = cent_bf + (size_t)c * 64 * D_DIM;
        #pragma unroll
        for (int h = 0; h < 2; ++h) {
            bf16x8 st[4];
            #pragma unroll
            for (int i = 0; i < 4; ++i) {
                int F  = (h * 4 + i) * 256 + tid;          // dst 16B unit
                int qd = F & 3, mm = (F >> 2) & 15, tt = (F >> 6) & 3, kk = F >> 8;
                int s16 = tt * 512 + mm * 32 + kk * 4 + qd; // src 16B unit
                st[i] = *(const bf16x8*)&src[s16 * 8];
            }
            #pragma unroll
            for (int i = 0; i < 4; ++i) {
                int F = (h * 4 + i) * 256 + tid;
                *(bf16x8*)&bstage[F * 8] = st[i];
            }
        }
        __syncthreads();
        #pragma unroll
        for (int ks = 0; ks < 8; ++ks) {
            #pragma unroll
            for (int t = 0; t < 4; ++t) {
                // lane-ordered contiguous 1KB fragment: conflict-free
                bf16x8 bfrag = *(const bf16x8*)&bstage[(ks * 256 + t * 64 + m15 * 4 + quad) * 8];
                acc[c * 4 + t] = __builtin_amdgcn_mfma_f32_16x16x32_bf16(
                    afrag[ks], bfrag, acc[c * 4 + t], 0, 0, 0);
            }
        }
        __syncthreads();
    }

    // ---- epilogue ----
    float rowsum[4] = {0.f, 0.f, 0.f, 0.f};
    #pragma unroll
    for (int t = 0; t < 16; ++t) {
        float c2v = c2[t * 16 + m15];
        #pragma unroll
        for (int r = 0; r < 4; ++r) {
            float sse = z2r[r] + c2v - 2.0f * acc[t][r];
            sse = fmaxf(sse, 0.0f);
            float u = 1.0f / (1.0f + sse);
            acc[t][r] = u;
            rowsum[r] += u;
        }
    }
    #pragma unroll
    for (int r = 0; r < 4; ++r) {
        float v = rowsum[r];
        v += __shfl_xor(v, 1, 64);
        v += __shfl_xor(v, 2, 64);
        v += __shfl_xor(v, 4, 64);
        v += __shfl_xor(v, 8, 64);
        rowsum[r] = 1.0f / v;
    }

    float colp[16];
    #pragma unroll
    for (int t = 0; t < 16; ++t) {
        float cp = 0.0f;
        #pragma unroll
        for (int r = 0; r < 4; ++r) {
            float qv = acc[t][r] * rowsum[r];
            cp += qv;
            q_out[(size_t)(row0 + quad * 4 + r) * K_CENT + t * 16 + m15] = qv;
        }
        cp += __shfl_xor(cp, 16, 64);
        cp += __shfl_xor(cp, 32, 64);
        colp[t] = cp;
    }
    if (quad == 0) {
        #pragma unroll
        for (int t = 0; t < 16; ++t) col_lds[wave][t * 16 + lane] = colp[t];
    }
    __syncthreads();
    float sp = col_lds[0][tid] + col_lds[1][tid] + col_lds[2][tid] + col_lds[3][tid];
    partials[(size_t)blockIdx.x * K_CENT + tid] = sp;   // coalesced, NO atomics
}

// ---------- colsum: s_col[k] = sum over 1024 blocks of partials[b][k] ----------
__global__ __launch_bounds__(256) void colsum_kernel(
        const float* __restrict__ partials,
        float* __restrict__ s_col) {
    const int tid = threadIdx.x;
    const float* base = partials + (size_t)blockIdx.x * 64 * K_CENT + tid;
    float s = 0.0f;
    #pragma unroll
    for (int h = 0; h < 8; ++h) {
        float v[8];
        #pragma unroll
        for (int i = 0; i < 8; ++i)
            v[i] = base[(h * 8 + i) * K_CENT];
        #pragma unroll
        for (int i = 0; i < 8; ++i) s += v[i];
    }
    atomicAdd(&s_col[tid], s);
}

// ---------- pass 2: p = rownorm(q^2 / s_col) ----------
__global__ __launch_bounds__(256) void pass2_kernel(
        const float* __restrict__ q,
        const float* __restrict__ s_col,
        float* __restrict__ p) {
    const int tid  = threadIdx.x;
    const int lane = tid & 63;
    const int wave = tid >> 6;
    const int wid  = blockIdx.x * 4 + wave;   // 0..8191

    const float4 sv = *(const float4*)(s_col + lane * 4);
    const float is0 = 1.0f / sv.x, is1 = 1.0f / sv.y,
                is2 = 1.0f / sv.z, is3 = 1.0f / sv.w;

    const float* qb = q + (size_t)wid * 8 * K_CENT + lane * 4;
    float*       pb = p + (size_t)wid * 8 * K_CENT + lane * 4;

    float4 qv[8];
    #pragma unroll
    for (int r = 0; r < 8; ++r) qv[r] = *(const float4*)(qb + r * K_CENT);

    #pragma unroll
    for (int r = 0; r < 8; ++r) {
        float sf0 = qv[r].x * qv[r].x * is0;
        float sf1 = qv[r].y * qv[r].y * is1;
        float sf2 = qv[r].z * qv[r].z * is2;
        float sf3 = qv[r].w * qv[r].w * is3;
        float part = sf0 + sf1 + sf2 + sf3;
        #pragma unroll
        for (int off = 32; off >= 1; off >>= 1) part += __shfl_xor(part, off, 64);
        const float rinv = 1.0f / part;
        float4 ov;
        ov.x = sf0 * rinv; ov.y = sf1 * rinv;
        ov.z = sf2 * rinv; ov.w = sf3 * rinv;
        *(float4*)(pb + r * K_CENT) = ov;
    }
}

extern "C" void kernel_launch(void* const* d_in, const int* in_sizes, int n_in,
                              void* d_out, int out_size, void* d_ws, size_t ws_size,
                              hipStream_t stream) {
    const float* z    = (const float*)d_in[0];
    const float* cent = (const float*)d_in[1];
    float* p_out = (float*)d_out;
    float* q_out = p_out + (size_t)N_ROWS * K_CENT;

    float* c2       = (float*)d_ws;
    float* s_col    = c2 + K_CENT;
    unsigned short* cent_bf = (unsigned short*)(s_col + K_CENT);
    float* partials = (float*)(cent_bf + K_CENT * D_DIM);   // 1 MB

    hipMemsetAsync(s_col, 0, K_CENT * sizeof(float), stream);
    c2_kernel<<<K_CENT, 64, 0, stream>>>(cent, c2, cent_bf);
    pass1_kernel<<<N_ROWS / 64, 256, 0, stream>>>(z, cent_bf, c2, partials, q_out);
    colsum_kernel<<<16, 256, 0, stream>>>(partials, s_col);
    pass2_kernel<<<N_ROWS / (4 * 8), 256, 0, stream>>>(q_out, s_col, p_out);
}